// Round 1
// baseline (3854.939 us; speedup 1.0000x reference)
//
#include <hip/hip_runtime.h>
#include <math.h>

#define DEV static __device__ __forceinline__

typedef __attribute__((ext_vector_type(4))) float f32x4;
typedef __attribute__((ext_vector_type(2))) float f32x2;
typedef __attribute__((ext_vector_type(8))) short bf16x8;

#define B_    2048
#define N_    100000
#define E_    512
#define KTOP  16
#define CHUNK 4096
#define NCHUNK 25
#define TOPC  24
#define NCAND (NCHUNK*TOPC)   /* 600 */
#define NSEL  48

DEV unsigned short f2bf(float f){
  union { float f; unsigned u; } v; v.f = f;
  unsigned r = v.u + 0x7fffu + ((v.u >> 16) & 1u);
  return (unsigned short)(r >> 16);
}

DEV f32x4 mfma16(bf16x8 a, bf16x8 b, f32x4 c){
  return __builtin_amdgcn_mfma_f32_16x16x32_bf16(a, b, c, 0, 0, 0);
}

// swizzled LDS helpers (byte ^= (row&7)<<4) — keeps 16B alignment, kills
// stride-2^k bank conflicts on ds_read_b128
DEV void lds_w8(unsigned short* base, int row, int k, int stride, bf16x8 v){
  char* p = (char*)base + (((row*stride + k)*2) ^ ((row & 7) << 4));
  *(bf16x8*)p = v;
}
DEV bf16x8 lds_r8(const unsigned short* base, int row, int k, int stride){
  const char* p = (const char*)base + (((row*stride + k)*2) ^ ((row & 7) << 4));
  return *(const bf16x8*)p;
}

// ---------------- row inverse L2 norm (wave per row) ----------------
__global__ void k_row_inv_norm(const float* __restrict__ x, float* __restrict__ inv, int rows){
  int gw = (blockIdx.x * 256 + threadIdx.x) >> 6;
  int lane = threadIdx.x & 63;
  if (gw >= rows) return;
  const float* r = x + (long)gw * E_;
  float s = 0.f;
  #pragma unroll
  for (int e = 0; e < E_; e += 256){
    f32x4 v = *(const f32x4*)(r + e + lane*4);
    s += v[0]*v[0] + v[1]*v[1] + v[2]*v[2] + v[3]*v[3];
  }
  #pragma unroll
  for (int o = 32; o; o >>= 1) s += __shfl_xor(s, o, 64);
  if (lane == 0) inv[gw] = 1.f / fmaxf(sqrtf(s), 1e-12f);
}

// ---------------- scale rows by inv-norm and convert to bf16 ----------------
__global__ void k_scale_bf16(const float* __restrict__ x, const float* __restrict__ inv,
                             unsigned short* __restrict__ out, long n){
  long i0 = ((long)blockIdx.x * 256 + threadIdx.x) * 8;
  long st = (long)gridDim.x * 2048;
  for (long i = i0; i < n; i += st){
    f32x4 a = *(const f32x4*)(x + i);
    f32x4 b = *(const f32x4*)(x + i + 4);
    float s = inv[i >> 9];     // row = i / 512, 512%8==0 so all 8 in one row
    bf16x8 o;
    o[0]=(short)f2bf(a[0]*s); o[1]=(short)f2bf(a[1]*s); o[2]=(short)f2bf(a[2]*s); o[3]=(short)f2bf(a[3]*s);
    o[4]=(short)f2bf(b[0]*s); o[5]=(short)f2bf(b[1]*s); o[6]=(short)f2bf(b[2]*s); o[7]=(short)f2bf(b[3]*s);
    *(bf16x8*)(out + i) = o;
  }
}

// ---------------- fp32 GEMM (encoders): C = act(A @ W + b), W is [K,N] ----------------
// A given as up to 2 row-major segments split along K (for the concat input of co1).
template<int NSEG, bool RELU>
__global__ __launch_bounds__(256) void k_gemm_f32(
    const float* __restrict__ A0, int K0,
    const float* __restrict__ A1, int K1,
    const float* __restrict__ Bw, const float* __restrict__ bias,
    float* __restrict__ C, int N, int Ktot)
{
  __shared__ float At[16][68];   // [k][m]
  __shared__ float Bt[16][68];   // [k][n]
  int bm = blockIdx.x * 64, bn = blockIdx.y * 64;
  int t = threadIdx.x;
  int tx = t & 15, ty = t >> 4;
  int arow = t >> 2, acol = (t & 3) * 4;
  float acc[4][4] = {};
  for (int k0 = 0; k0 < Ktot; k0 += 16){
    int gk = k0 + acol;
    const float* src = A0; int kk = gk, ld = K0;
    if (NSEG == 2 && gk >= K0){ src = A1; kk = gk - K0; ld = K1; }
    f32x4 av = *(const f32x4*)(src + (long)(bm + arow) * ld + kk);
    At[acol+0][arow] = av[0]; At[acol+1][arow] = av[1];
    At[acol+2][arow] = av[2]; At[acol+3][arow] = av[3];
    f32x4 bv = *(const f32x4*)(Bw + (long)(k0 + ty) * N + bn + tx*4);
    *(f32x4*)&Bt[ty][tx*4] = bv;
    __syncthreads();
    #pragma unroll
    for (int k = 0; k < 16; k++){
      f32x4 a = *(const f32x4*)&At[k][ty*4];
      f32x4 b = *(const f32x4*)&Bt[k][tx*4];
      #pragma unroll
      for (int i = 0; i < 4; i++)
        #pragma unroll
        for (int j = 0; j < 4; j++)
          acc[i][j] += a[i]*b[j];
    }
    __syncthreads();
  }
  #pragma unroll
  for (int i = 0; i < 4; i++){
    int m = bm + ty*4 + i;
    #pragma unroll
    for (int j = 0; j < 4; j++){
      int n = bn + tx*4 + j;
      float v = acc[i][j] + bias[n];
      if (RELU) v = fmaxf(v, 0.f);
      C[(long)m*N + n] = v;
    }
  }
}

// ---------------- transpose fp32 [K,N] -> bf16 [N,K] ----------------
__global__ void k_transpose_bf16(const float* __restrict__ W, unsigned short* __restrict__ WT, int K, int N){
  __shared__ float tile[32][33];
  int k0 = blockIdx.x * 32, n0 = blockIdx.y * 32;
  int tx = threadIdx.x & 31, ty = threadIdx.x >> 5;
  #pragma unroll
  for (int r = 0; r < 32; r += 8) tile[ty + r][tx] = W[(long)(k0 + ty + r) * N + n0 + tx];
  __syncthreads();
  #pragma unroll
  for (int r = 0; r < 32; r += 8) WT[(long)(n0 + ty + r) * K + k0 + tx] = f2bf(tile[tx][ty + r]);
}

// ---------------- bf16 MFMA NT GEMM: C = act(A @ Bt^T + bias) ----------------
// A: [M,K] — either bf16 (AF32=false) or up to 3 fp32 row-major segments
// (AF32=true, converted to bf16 while staging). Bt: [N,K] bf16 (pre-transposed).
template<int NSEG, bool AF32, bool RELU, bool OUTBF16>
__global__ __launch_bounds__(256) void k_gemm_bf16(
    const void* __restrict__ A0p, int K0,
    const void* __restrict__ A1p, int K1,
    const void* __restrict__ A2p,
    const unsigned short* __restrict__ Bt, const float* __restrict__ bias,
    void* __restrict__ Cp, int N, int Ktot)
{
  __shared__ unsigned short Ash[64*64];
  __shared__ unsigned short Bsh[64*64];
  int bm = blockIdx.x * 64, bn = blockIdx.y * 64;
  int t = threadIdx.x, lane = t & 63, wid = t >> 6;
  int wr = wid >> 1, wc = wid & 1;
  int r16 = lane & 15, khalf = lane >> 4;
  int srow = t >> 2, skc = (t & 3) * 16;
  f32x4 acc00 = {0,0,0,0}, acc01 = {0,0,0,0}, acc10 = {0,0,0,0}, acc11 = {0,0,0,0};

  for (int k0 = 0; k0 < Ktot; k0 += 64){
    int gk = k0 + skc;
    if (!AF32){
      const unsigned short* A = (const unsigned short*)A0p;
      const unsigned short* s = A + (long)(bm + srow) * Ktot + gk;
      lds_w8(Ash, srow, skc,     64, *(const bf16x8*)s);
      lds_w8(Ash, srow, skc + 8, 64, *(const bf16x8*)(s + 8));
    } else {
      const float* s; int kk, ld;
      if (NSEG >= 2 && gk >= K0){
        if (NSEG == 3 && gk >= K0 + K1){ s = (const float*)A2p; kk = gk - K0 - K1; ld = Ktot - K0 - K1; }
        else                           { s = (const float*)A1p; kk = gk - K0;      ld = K1; }
      } else { s = (const float*)A0p; kk = gk; ld = K0; }
      const float* p = s + (long)(bm + srow) * ld + kk;
      f32x4 f0 = *(const f32x4*)p, f1 = *(const f32x4*)(p+4), f2 = *(const f32x4*)(p+8), f3 = *(const f32x4*)(p+12);
      bf16x8 v0, v1;
      v0[0]=(short)f2bf(f0[0]); v0[1]=(short)f2bf(f0[1]); v0[2]=(short)f2bf(f0[2]); v0[3]=(short)f2bf(f0[3]);
      v0[4]=(short)f2bf(f1[0]); v0[5]=(short)f2bf(f1[1]); v0[6]=(short)f2bf(f1[2]); v0[7]=(short)f2bf(f1[3]);
      v1[0]=(short)f2bf(f2[0]); v1[1]=(short)f2bf(f2[1]); v1[2]=(short)f2bf(f2[2]); v1[3]=(short)f2bf(f2[3]);
      v1[4]=(short)f2bf(f3[0]); v1[5]=(short)f2bf(f3[1]); v1[6]=(short)f2bf(f3[2]); v1[7]=(short)f2bf(f3[3]);
      lds_w8(Ash, srow, skc, 64, v0);
      lds_w8(Ash, srow, skc + 8, 64, v1);
    }
    const unsigned short* bs = Bt + (long)(bn + srow) * Ktot + gk;
    lds_w8(Bsh, srow, skc,     64, *(const bf16x8*)bs);
    lds_w8(Bsh, srow, skc + 8, 64, *(const bf16x8*)(bs + 8));
    __syncthreads();
    #pragma unroll
    for (int ks = 0; ks < 2; ks++){
      int kb = ks*32 + khalf*8;
      bf16x8 a0 = lds_r8(Ash, wr*32 +      r16, kb, 64);
      bf16x8 a1 = lds_r8(Ash, wr*32 + 16 + r16, kb, 64);
      bf16x8 b0 = lds_r8(Bsh, wc*32 +      r16, kb, 64);
      bf16x8 b1 = lds_r8(Bsh, wc*32 + 16 + r16, kb, 64);
      acc00 = mfma16(a0, b0, acc00);
      acc01 = mfma16(a0, b1, acc01);
      acc10 = mfma16(a1, b0, acc10);
      acc11 = mfma16(a1, b1, acc11);
    }
    __syncthreads();
  }
  #pragma unroll
  for (int r = 0; r < 4; r++){
    int mA = bm + wr*32 +      khalf*4 + r;
    int mB = bm + wr*32 + 16 + khalf*4 + r;
    int nA = bn + wc*32 +      r16;
    int nB = bn + wc*32 + 16 + r16;
    float v00 = acc00[r] + bias[nA]; float v01 = acc01[r] + bias[nB];
    float v10 = acc10[r] + bias[nA]; float v11 = acc11[r] + bias[nB];
    if (RELU){ v00 = fmaxf(v00,0.f); v01 = fmaxf(v01,0.f); v10 = fmaxf(v10,0.f); v11 = fmaxf(v11,0.f); }
    if (OUTBF16){
      unsigned short* C = (unsigned short*)Cp;
      C[(long)mA*N + nA] = f2bf(v00); C[(long)mA*N + nB] = f2bf(v01);
      C[(long)mB*N + nA] = f2bf(v10); C[(long)mB*N + nB] = f2bf(v11);
    } else {
      float* C = (float*)Cp;
      C[(long)mA*N + nA] = v00; C[(long)mA*N + nB] = v01;
      C[(long)mB*N + nA] = v10; C[(long)mB*N + nB] = v11;
    }
  }
}

// ---------------- similarity GEMM + fused per-chunk top-24 ----------------
// block = (64 query rows) x (one 4096-col chunk). Q fragments live in
// registers (full K=512); corpus streamed via double-buffered swizzled LDS.
__global__ __launch_bounds__(256, 1) void k_sim_topk(
    const unsigned short* __restrict__ Qb, const unsigned short* __restrict__ Cb,
    float* __restrict__ candS, int* __restrict__ candI)
{
  __shared__ unsigned short Csh[2][64*512];  // 2 x 64KB
  __shared__ float scS[64][68];
  __shared__ float topS[64][TOPC];
  __shared__ int   topI[64][TOPC];
  int rowtile = blockIdx.x, chunk = blockIdx.y;
  int t = threadIdx.x, lane = t & 63, wid = t >> 6;
  int wr = wid >> 1, wc = wid & 1;
  int r16 = lane & 15, khalf = lane >> 4;

  for (int i = t; i < 64*TOPC; i += 256){ (&topS[0][0])[i] = -__builtin_inff(); (&topI[0][0])[i] = 0; }

  // Q fragments -> registers: 2 row-tiles x 16 k-steps (K=32 each)
  bf16x8 areg[2][16];
  {
    const unsigned short* qb = Qb + ((long)(rowtile*64 + wr*32) << 9);
    #pragma unroll
    for (int mt = 0; mt < 2; mt++)
      #pragma unroll
      for (int ks = 0; ks < 16; ks++)
        areg[mt][ks] = *(const bf16x8*)(qb + ((long)(mt*16 + r16) << 9) + ks*32 + khalf*8);
  }

  int jbase0 = chunk * CHUNK;
  int njt = (jbase0 + CHUNK <= N_) ? (CHUNK/64) : ((N_ - jbase0 + 63) / 64);

  auto stage = [&](int buf, int jt){
    int r = t >> 2, kp = (t & 3) * 128;
    int j = jbase0 + jt*64 + r;
    unsigned short* dst = Csh[buf];
    if (j < N_){
      const unsigned short* src = Cb + ((long)j << 9) + kp;
      #pragma unroll
      for (int i = 0; i < 16; i++)
        lds_w8(dst, r, kp + i*8, 512, *(const bf16x8*)(src + i*8));
    } else {
      bf16x8 z = {0,0,0,0,0,0,0,0};
      #pragma unroll
      for (int i = 0; i < 16; i++)
        lds_w8(dst, r, kp + i*8, 512, z);
    }
  };

  stage(0, 0);
  __syncthreads();

  float rmin = -__builtin_inff();   // per-row running min of top-24 (threads 0..63)

  for (int jt = 0; jt < njt; jt++){
    int cur = jt & 1;
    f32x4 acc00 = {0,0,0,0}, acc01 = {0,0,0,0}, acc10 = {0,0,0,0}, acc11 = {0,0,0,0};
    const unsigned short* cbuf = Csh[cur];
    #pragma unroll
    for (int ks = 0; ks < 16; ks++){
      int kb = ks*32 + khalf*8;
      bf16x8 b0 = lds_r8(cbuf, wc*32 +      r16, kb, 512);
      bf16x8 b1 = lds_r8(cbuf, wc*32 + 16 + r16, kb, 512);
      acc00 = mfma16(areg[0][ks], b0, acc00);
      acc01 = mfma16(areg[0][ks], b1, acc01);
      acc10 = mfma16(areg[1][ks], b0, acc10);
      acc11 = mfma16(areg[1][ks], b1, acc11);
    }
    #pragma unroll
    for (int r = 0; r < 4; r++){
      scS[wr*32 +      khalf*4 + r][wc*32 +      r16] = acc00[r];
      scS[wr*32 +      khalf*4 + r][wc*32 + 16 + r16] = acc01[r];
      scS[wr*32 + 16 + khalf*4 + r][wc*32 +      r16] = acc10[r];
      scS[wr*32 + 16 + khalf*4 + r][wc*32 + 16 + r16] = acc11[r];
    }
    __syncthreads();
    if (jt + 1 < njt) stage(cur ^ 1, jt + 1);
    if (t < 64){
      int row = t;
      int jb = jbase0 + jt*64;
      for (int c4 = 0; c4 < 64; c4 += 4){
        f32x4 v = *(const f32x4*)&scS[row][c4];
        float m = fmaxf(fmaxf(v[0], v[1]), fmaxf(v[2], v[3]));
        if (m > rmin){
          #pragma unroll
          for (int u = 0; u < 4; u++){
            float s = v[u]; int j = jb + c4 + u;
            if (s > rmin && j < N_){
              int slot = 0; float mn = topS[row][0];
              for (int q = 1; q < TOPC; q++){ float ts = topS[row][q]; if (ts < mn){ mn = ts; slot = q; } }
              topS[row][slot] = s; topI[row][slot] = j;
              mn = topS[row][0];
              for (int q = 1; q < TOPC; q++) mn = fminf(mn, topS[row][q]);
              rmin = mn;
            }
          }
        }
      }
    }
    __syncthreads();
  }
  for (int i = t; i < 64*TOPC; i += 256){
    int row = i / TOPC, q = i - row*TOPC;
    long o = (((long)(rowtile*64 + row)) * NCHUNK + chunk) * TOPC + q;
    candS[o] = topS[row][q];
    candI[o] = topI[row][q];
  }
}

// ---------------- merge 600 approx candidates -> top-48 -> fp64 rescore -> exact top-16 ----------------
__global__ __launch_bounds__(256) void k_finalize(
    const float* __restrict__ candS, const int* __restrict__ candI,
    const float* __restrict__ contrast, const float* __restrict__ corpus,
    float* __restrict__ outScore, float* __restrict__ outIdxF, int* __restrict__ outIdxI)
{
  __shared__ float cs[NCAND];
  __shared__ int   ci[NCAND];
  __shared__ float q[E_];
  __shared__ float wS[4]; __shared__ int wP[4];
  __shared__ double wD[4];
  __shared__ int sel[NSEL];
  __shared__ double exS[NSEL];
  __shared__ double qn_sh;
  int row = blockIdx.x, t = threadIdx.x, lane = t & 63, wid = t >> 6;

  for (int i = t; i < NCAND; i += 256){ cs[i] = candS[(long)row*NCAND + i]; ci[i] = candI[(long)row*NCAND + i]; }
  for (int i = t; i < E_; i += 256) q[i] = contrast[(long)row*E_ + i];
  __syncthreads();

  double qs = 0.0;
  for (int i = t; i < E_; i += 256){ double v = q[i]; qs += v*v; }
  #pragma unroll
  for (int o = 32; o; o >>= 1) qs += __shfl_xor(qs, o, 64);
  if (lane == 0) wD[wid] = qs;
  __syncthreads();
  if (t == 0) qn_sh = fmax(sqrt(wD[0]+wD[1]+wD[2]+wD[3]), 1e-12);
  __syncthreads();

  for (int it = 0; it < NSEL; it++){
    float bs = -__builtin_inff(); int bp = -1;
    for (int i = t; i < NCAND; i += 256){
      float s = cs[i];
      if (s > bs || (s == bs && bp >= 0 && ci[i] < ci[bp])){ bs = s; bp = i; }
    }
    #pragma unroll
    for (int o = 32; o; o >>= 1){
      float os = __shfl_xor(bs, o, 64);
      int   op = __shfl_xor(bp, o, 64);
      bool take = false;
      if (op >= 0){
        if (os > bs) take = true;
        else if (os == bs && (bp < 0 || ci[op] < ci[bp])) take = true;
      }
      if (take){ bs = os; bp = op; }
    }
    if (lane == 0){ wS[wid] = bs; wP[wid] = bp; }
    __syncthreads();
    if (t == 0){
      float s = -__builtin_inff(); int p = -1;
      for (int w = 0; w < 4; w++){
        float os = wS[w]; int op = wP[w];
        if (op >= 0 && (os > s || (os == s && (p < 0 || ci[op] < ci[p])))){ s = os; p = op; }
      }
      sel[it] = (p >= 0) ? ci[p] : 0;
      if (p >= 0) cs[p] = -__builtin_inff();
    }
    __syncthreads();
  }

  for (int c = wid; c < NSEL; c += 4){
    int j = sel[c];
    const float* cr = corpus + ((long)j << 9);
    int e = lane * 8;
    f32x4 v1 = *(const f32x4*)(cr + e);
    f32x4 v2 = *(const f32x4*)(cr + e + 4);
    f32x4 q1 = *(const f32x4*)(&q[e]);
    f32x4 q2 = *(const f32x4*)(&q[e+4]);
    double ds = 0.0, dn = 0.0;
    #pragma unroll
    for (int u = 0; u < 4; u++){ ds += (double)v1[u]*(double)q1[u]; dn += (double)v1[u]*(double)v1[u]; }
    #pragma unroll
    for (int u = 0; u < 4; u++){ ds += (double)v2[u]*(double)q2[u]; dn += (double)v2[u]*(double)v2[u]; }
    #pragma unroll
    for (int o = 32; o; o >>= 1){ ds += __shfl_xor(ds, o, 64); dn += __shfl_xor(dn, o, 64); }
    if (lane == 0) exS[c] = ds / (fmax(sqrt(dn), 1e-12) * qn_sh);
  }
  __syncthreads();

  if (t == 0){
    double bsv[KTOP]; int biv[KTOP];
    #pragma unroll
    for (int i = 0; i < KTOP; i++){ bsv[i] = -__builtin_inf(); biv[i] = 0x7fffffff; }
    for (int c = 0; c < NSEL; c++){
      double s = exS[c]; int j = sel[c];
      int pos = KTOP;
      for (int i = 0; i < KTOP; i++){
        if (s > bsv[i] || (s == bsv[i] && j < biv[i])){ pos = i; break; }
      }
      if (pos < KTOP){
        for (int i = KTOP-1; i > pos; i--){ bsv[i] = bsv[i-1]; biv[i] = biv[i-1]; }
        bsv[pos] = s; biv[pos] = j;
      }
    }
    for (int i = 0; i < KTOP; i++){
      outScore[(long)row*KTOP + i] = (float)bsv[i];
      outIdxF [(long)row*KTOP + i] = (float)biv[i];
      outIdxI [(long)row*KTOP + i] = biv[i];
    }
  }
}

// ---------------- gather retrieved corpus rows (un-normalized) -> bf16 ----------------
__global__ void k_gather_bf16(const float* __restrict__ corpus, const int* __restrict__ topidx,
                              unsigned short* __restrict__ out){
  int row = blockIdx.x, t = threadIdx.x;
  #pragma unroll
  for (int seg = 0; seg < KTOP; seg++){
    int j = topidx[row*KTOP + seg];
    const float* src = corpus + ((long)j << 9);
    unsigned short* dst = out + ((long)row << 13) + (seg << 9);
    int e = t * 2;
    f32x2 v = *(const f32x2*)(src + e);
    dst[e] = f2bf(v[0]); dst[e+1] = f2bf(v[1]);
  }
}

// ---------------- final gemv: outcome = z2 @ op_w3 + b3 ----------------
__global__ void k_gemv_out(const float* __restrict__ z2, const float* __restrict__ w3,
                           const float* __restrict__ b3, float* __restrict__ outc){
  int gw = (blockIdx.x * 256 + threadIdx.x) >> 6, lane = threadIdx.x & 63;
  if (gw >= B_) return;
  const float* r = z2 + (long)gw * 512;
  int e = lane * 8;
  f32x4 a1 = *(const f32x4*)(r + e),  a2 = *(const f32x4*)(r + e + 4);
  f32x4 b1 = *(const f32x4*)(w3 + e), b2 = *(const f32x4*)(w3 + e + 4);
  float s = a1[0]*b1[0]+a1[1]*b1[1]+a1[2]*b1[2]+a1[3]*b1[3]
          + a2[0]*b2[0]+a2[1]*b2[1]+a2[2]*b2[2]+a2[3]*b2[3];
  #pragma unroll
  for (int o = 32; o; o >>= 1) s += __shfl_xor(s, o, 64);
  if (lane == 0) outc[gw] = s + b3[0];
}

extern "C" void kernel_launch(void* const* d_in, const int* in_sizes, int n_in,
                              void* d_out, int out_size, void* d_ws, size_t ws_size,
                              hipStream_t stream)
{
  (void)in_sizes; (void)n_in; (void)out_size; (void)ws_size;
  const float* patient     = (const float*)d_in[0];
  const float* treatment   = (const float*)d_in[1];
  const float* confounders = (const float*)d_in[2];
  const float* corpus      = (const float*)d_in[3];
  const float* pe_w1 = (const float*)d_in[4];  const float* pe_b1 = (const float*)d_in[5];
  const float* pe_w2 = (const float*)d_in[6];  const float* pe_b2 = (const float*)d_in[7];
  const float* te_w  = (const float*)d_in[8];  const float* te_b  = (const float*)d_in[9];
  const float* ce_w  = (const float*)d_in[10]; const float* ce_b  = (const float*)d_in[11];
  const float* co_w1 = (const float*)d_in[12]; const float* co_b1 = (const float*)d_in[13];
  const float* co_w2 = (const float*)d_in[14]; const float* co_b2 = (const float*)d_in[15];
  const float* re_w  = (const float*)d_in[16]; const float* re_b  = (const float*)d_in[17];
  const float* op_w1 = (const float*)d_in[18]; const float* op_b1 = (const float*)d_in[19];
  const float* op_w2 = (const float*)d_in[20]; const float* op_b2 = (const float*)d_in[21];
  const float* op_w3 = (const float*)d_in[22]; const float* op_b3 = (const float*)d_in[23];

  float* out = (float*)d_out;
  float* out_outcome = out;
  float* out_scores  = out + 2048;
  float* out_idxf    = out + 2048 + 32768;
  float* out_contr   = out + 2048 + 32768 + 32768;

  char* ws = (char*)d_ws;
  const size_t MB = 1024*1024;
  // [0, 98MB): corpus_bf16 during retrieval; reused for the post-retrieval phase
  unsigned short* cb    = (unsigned short*)(ws + 0);        // 97.7 MB
  unsigned short* retr  = (unsigned short*)(ws + 0);        // 32 MB (after sim)
  unsigned short* reT   = (unsigned short*)(ws + 34*MB);    // 16 MB
  unsigned short* op1T  = (unsigned short*)(ws + 51*MB);    // 6.3 MB
  unsigned short* op2T  = (unsigned short*)(ws + 58*MB);    // 1 MB
  float* t2     = (float*)(ws + 60*MB);                     // 8 MB (dead before re_out)
  float* re_out = (float*)(ws + 60*MB);                     // 8 MB
  unsigned short* z1 = (unsigned short*)(ws + 69*MB);       // 4 MB
  float* z2     = (float*)(ws + 74*MB);                     // 4 MB
  float* te_emb = (float*)(ws + 98*MB);                     // 8 MB persist
  float* ce_emb = (float*)(ws + 107*MB);                    // 8 MB persist
  float* t1     = (float*)(ws + 116*MB);                    // 8 MB (phase A)
  float* pe_emb = (float*)(ws + 125*MB);                    // 8 MB (phase A)
  unsigned short* qb = (unsigned short*)(ws + 116*MB);      // 2 MB (phase B, t1 dead)
  float* invq  = (float*)(ws + 119*MB);
  float* invc  = (float*)(ws + 120*MB);
  float* candS = (float*)(ws + 121*MB);                     // 4.9 MB
  int*   candI = (int*)(ws + 127*MB);                       // 4.9 MB
  int*   topidx= (int*)(ws + 133*MB);                       // 128 KB

  dim3 blk(256);
  // --- encoders (fp32, query-precision-critical) ---
  k_gemm_f32<1,true ><<<dim3(32,16), blk, 0, stream>>>(patient, 320, nullptr, 0, pe_w1, pe_b1, t1, 1024, 320);
  k_gemm_f32<1,false><<<dim3(32,16), blk, 0, stream>>>(t1, 1024, nullptr, 0, pe_w2, pe_b2, pe_emb, 1024, 1024);
  k_gemm_f32<1,false><<<dim3(32,16), blk, 0, stream>>>(treatment, 64, nullptr, 0, te_w, te_b, te_emb, 1024, 64);
  k_gemm_f32<1,false><<<dim3(32,16), blk, 0, stream>>>(confounders, 256, nullptr, 0, ce_w, ce_b, ce_emb, 1024, 256);
  k_gemm_f32<2,true ><<<dim3(32,16), blk, 0, stream>>>(pe_emb, 1024, ce_emb, 1024, co_w1, co_b1, t2, 1024, 2048);
  k_gemm_f32<1,false><<<dim3(32, 8), blk, 0, stream>>>(t2, 1024, nullptr, 0, co_w2, co_b2, out_contr, 512, 1024);
  // --- normalize + bf16 convert ---
  k_row_inv_norm<<<dim3(512),   blk, 0, stream>>>(out_contr, invq, 2048);
  k_row_inv_norm<<<dim3(25000), blk, 0, stream>>>(corpus, invc, 100000);
  k_scale_bf16<<<dim3(512),  blk, 0, stream>>>(out_contr, invq, qb, (long)2048*512);
  k_scale_bf16<<<dim3(2048), blk, 0, stream>>>(corpus, invc, cb, (long)100000*512);
  // --- similarity + top-k ---
  k_sim_topk<<<dim3(32,25), blk, 0, stream>>>(qb, cb, candS, candI);
  k_finalize<<<dim3(2048), blk, 0, stream>>>(candS, candI, out_contr, corpus, out_scores, out_idxf, topidx);
  // --- retrieval encoder + outcome head (bf16 MFMA) ---
  k_gather_bf16<<<dim3(2048), blk, 0, stream>>>(corpus, topidx, retr);
  k_transpose_bf16<<<dim3(256,32), blk, 0, stream>>>(re_w,  reT,  8192, 1024);
  k_transpose_bf16<<<dim3(96,32),  blk, 0, stream>>>(op_w1, op1T, 3072, 1024);
  k_transpose_bf16<<<dim3(32,16),  blk, 0, stream>>>(op_w2, op2T, 1024, 512);
  k_gemm_bf16<1,false,false,false><<<dim3(32,16), blk, 0, stream>>>(retr, 8192, nullptr, 0, nullptr, reT, re_b, re_out, 1024, 8192);
  k_gemm_bf16<3,true, true, true ><<<dim3(32,16), blk, 0, stream>>>(te_emb, 1024, ce_emb, 1024, re_out, op1T, op_b1, z1, 1024, 3072);
  k_gemm_bf16<1,false,true, false><<<dim3(32, 8), blk, 0, stream>>>(z1, 1024, nullptr, 0, nullptr, op2T, op_b2, z2, 512, 1024);
  k_gemv_out<<<dim3(512), blk, 0, stream>>>(z2, op_w3, op_b3, out_outcome);
}

// Round 2
// 2480.480 us; speedup vs baseline: 1.5541x; 1.5541x over previous
//
#include <hip/hip_runtime.h>
#include <math.h>

#define DEV static __device__ __forceinline__

typedef __attribute__((ext_vector_type(4))) float f32x4;
typedef __attribute__((ext_vector_type(2))) float f32x2;
typedef __attribute__((ext_vector_type(8))) short bf16x8;

#define B_    2048
#define N_    100000
#define E_    512
#define KTOP  16
#define CHUNK 12500
#define NCHUNK 8
#define TOPC  24
#define NCAND (NCHUNK*TOPC)   /* 192 */
#define NSEL  48

DEV unsigned short f2bf(float f){
  union { float f; unsigned u; } v; v.f = f;
  unsigned r = v.u + 0x7fffu + ((v.u >> 16) & 1u);
  return (unsigned short)(r >> 16);
}

DEV f32x4 mfma16(bf16x8 a, bf16x8 b, f32x4 c){
  return __builtin_amdgcn_mfma_f32_16x16x32_bf16(a, b, c, 0, 0, 0);
}

// swizzled LDS helpers for bf16 tiles (byte ^= (row&7)<<4)
DEV void lds_w8(unsigned short* base, int row, int k, int stride, bf16x8 v){
  char* p = (char*)base + (((row*stride + k)*2) ^ ((row & 7) << 4));
  *(bf16x8*)p = v;
}
DEV bf16x8 lds_r8(const unsigned short* base, int row, int k, int stride){
  const char* p = (const char*)base + (((row*stride + k)*2) ^ ((row & 7) << 4));
  return *(const bf16x8*)p;
}

// global -> LDS direct DMA, 16B per lane. LDS dest must be wave-uniform base
// (lane*16 implicit). Integer-cast to as(3) is valid: LDS aperture is 4GiB
// aligned so low 32 bits of the flat pointer == LDS offset (CK's pattern).
DEV void gload_lds16(const void* g, void* l){
  __builtin_amdgcn_global_load_lds(
      (const __attribute__((address_space(1))) void*)(unsigned long long)(uintptr_t)g,
      (__attribute__((address_space(3))) void*)(unsigned)(uintptr_t)l,
      16, 0, 0);
}

// score-tile LDS swizzle: word idx = (row*64+col) ^ ((row&7)<<2); bits 0-1 of
// col untouched so f32x4 at col%4==0 stays contiguous/aligned.
DEV int sc_idx(int row, int col){ return ((row << 6) | col) ^ ((row & 7) << 2); }

// ---------------- fused row L2-normalize + bf16 convert (1 wave / row) -------
__global__ void k_norm_bf16(const float* __restrict__ x, unsigned short* __restrict__ out, int rows){
  int gw = (blockIdx.x * 256 + threadIdx.x) >> 6;
  int lane = threadIdx.x & 63;
  if (gw >= rows) return;
  const float* r = x + (long)gw * E_;
  f32x4 v0 = *(const f32x4*)(r + lane*8);
  f32x4 v1 = *(const f32x4*)(r + lane*8 + 4);
  float s = v0[0]*v0[0]+v0[1]*v0[1]+v0[2]*v0[2]+v0[3]*v0[3]
          + v1[0]*v1[0]+v1[1]*v1[1]+v1[2]*v1[2]+v1[3]*v1[3];
  #pragma unroll
  for (int o = 32; o; o >>= 1) s += __shfl_xor(s, o, 64);
  float inv = 1.f / fmaxf(sqrtf(s), 1e-12f);
  bf16x8 o;
  o[0]=(short)f2bf(v0[0]*inv); o[1]=(short)f2bf(v0[1]*inv); o[2]=(short)f2bf(v0[2]*inv); o[3]=(short)f2bf(v0[3]*inv);
  o[4]=(short)f2bf(v1[0]*inv); o[5]=(short)f2bf(v1[1]*inv); o[6]=(short)f2bf(v1[2]*inv); o[7]=(short)f2bf(v1[3]*inv);
  *(bf16x8*)(out + (long)gw*E_ + lane*8) = o;
}

// ---------------- fp32 GEMM (encoders): C = act(A @ W + b), W is [K,N] ------
// 128x64 tile, 8x4 acc per thread. A as up to 2 row-major K-segments.
template<int NSEG, bool RELU>
__global__ __launch_bounds__(256) void k_gemm_f32(
    const float* __restrict__ A0, int K0,
    const float* __restrict__ A1, int K1,
    const float* __restrict__ Bw, const float* __restrict__ bias,
    float* __restrict__ C, int N, int Ktot)
{
  __shared__ float At[16][132];   // [k][m]
  __shared__ float Bt[16][68];    // [k][n]
  int bm = blockIdx.x * 128, bn = blockIdx.y * 64;
  int t = threadIdx.x;
  int tx = t & 15, ty = t >> 4;
  int ar = t >> 1, ac = (t & 1) * 8;
  float acc[8][4] = {};
  for (int k0 = 0; k0 < Ktot; k0 += 16){
    {
      int gk = k0 + ac;
      const float* src = A0; int kk = gk, ld = K0;
      if (NSEG == 2 && gk >= K0){ src = A1; kk = gk - K0; ld = K1; }
      const float* p = src + (long)(bm + ar) * ld + kk;
      f32x4 v0 = *(const f32x4*)p;
      f32x4 v1 = *(const f32x4*)(p + 4);
      #pragma unroll
      for (int i = 0; i < 4; i++) At[ac+i][ar] = v0[i];
      #pragma unroll
      for (int i = 0; i < 4; i++) At[ac+4+i][ar] = v1[i];
    }
    *(f32x4*)&Bt[ty][tx*4] = *(const f32x4*)(Bw + (long)(k0 + ty) * N + bn + tx*4);
    __syncthreads();
    #pragma unroll
    for (int k = 0; k < 16; k++){
      f32x4 a0 = *(const f32x4*)&At[k][ty*8];
      f32x4 a1 = *(const f32x4*)&At[k][ty*8+4];
      f32x4 b  = *(const f32x4*)&Bt[k][tx*4];
      #pragma unroll
      for (int i = 0; i < 4; i++){
        #pragma unroll
        for (int j = 0; j < 4; j++){ acc[i][j] += a0[i]*b[j]; acc[4+i][j] += a1[i]*b[j]; }
      }
    }
    __syncthreads();
  }
  f32x4 bi = *(const f32x4*)(bias + bn + tx*4);
  #pragma unroll
  for (int i = 0; i < 8; i++){
    int m = bm + ty*8 + i;
    f32x4 v;
    #pragma unroll
    for (int j = 0; j < 4; j++){
      float x = acc[i][j] + bi[j];
      v[j] = RELU ? fmaxf(x, 0.f) : x;
    }
    *(f32x4*)(C + (long)m*N + bn + tx*4) = v;
  }
}

// ---------------- transpose fp32 [K,N] -> bf16 [N,K] ----------------
__global__ void k_transpose_bf16(const float* __restrict__ W, unsigned short* __restrict__ WT, int K, int N){
  __shared__ float tile[32][33];
  int k0 = blockIdx.x * 32, n0 = blockIdx.y * 32;
  int tx = threadIdx.x & 31, ty = threadIdx.x >> 5;
  #pragma unroll
  for (int r = 0; r < 32; r += 8) tile[ty + r][tx] = W[(long)(k0 + ty + r) * N + n0 + tx];
  __syncthreads();
  #pragma unroll
  for (int r = 0; r < 32; r += 8) WT[(long)(n0 + ty + r) * K + k0 + tx] = f2bf(tile[tx][ty + r]);
}

// ---------------- bf16 MFMA NT GEMM: C = act(A @ Bt^T + bias) ----------------
template<int NSEG, bool AF32, bool RELU, bool OUTBF16>
__global__ __launch_bounds__(256) void k_gemm_bf16(
    const void* __restrict__ A0p, int K0,
    const void* __restrict__ A1p, int K1,
    const void* __restrict__ A2p,
    const unsigned short* __restrict__ Bt, const float* __restrict__ bias,
    void* __restrict__ Cp, int N, int Ktot)
{
  __shared__ unsigned short Ash[64*64];
  __shared__ unsigned short Bsh[64*64];
  int bm = blockIdx.x * 64, bn = blockIdx.y * 64;
  int t = threadIdx.x, lane = t & 63, wid = t >> 6;
  int wr = wid >> 1, wc = wid & 1;
  int r16 = lane & 15, khalf = lane >> 4;
  int srow = t >> 2, skc = (t & 3) * 16;
  f32x4 acc00 = {0,0,0,0}, acc01 = {0,0,0,0}, acc10 = {0,0,0,0}, acc11 = {0,0,0,0};

  for (int k0 = 0; k0 < Ktot; k0 += 64){
    int gk = k0 + skc;
    if (!AF32){
      const unsigned short* A = (const unsigned short*)A0p;
      const unsigned short* s = A + (long)(bm + srow) * Ktot + gk;
      lds_w8(Ash, srow, skc,     64, *(const bf16x8*)s);
      lds_w8(Ash, srow, skc + 8, 64, *(const bf16x8*)(s + 8));
    } else {
      const float* s; int kk, ld;
      if (NSEG >= 2 && gk >= K0){
        if (NSEG == 3 && gk >= K0 + K1){ s = (const float*)A2p; kk = gk - K0 - K1; ld = Ktot - K0 - K1; }
        else                           { s = (const float*)A1p; kk = gk - K0;      ld = K1; }
      } else { s = (const float*)A0p; kk = gk; ld = K0; }
      const float* p = s + (long)(bm + srow) * ld + kk;
      f32x4 f0 = *(const f32x4*)p, f1 = *(const f32x4*)(p+4), f2 = *(const f32x4*)(p+8), f3 = *(const f32x4*)(p+12);
      bf16x8 v0, v1;
      v0[0]=(short)f2bf(f0[0]); v0[1]=(short)f2bf(f0[1]); v0[2]=(short)f2bf(f0[2]); v0[3]=(short)f2bf(f0[3]);
      v0[4]=(short)f2bf(f1[0]); v0[5]=(short)f2bf(f1[1]); v0[6]=(short)f2bf(f1[2]); v0[7]=(short)f2bf(f1[3]);
      v1[0]=(short)f2bf(f2[0]); v1[1]=(short)f2bf(f2[1]); v1[2]=(short)f2bf(f2[2]); v1[3]=(short)f2bf(f2[3]);
      v1[4]=(short)f2bf(f3[0]); v1[5]=(short)f2bf(f3[1]); v1[6]=(short)f2bf(f3[2]); v1[7]=(short)f2bf(f3[3]);
      lds_w8(Ash, srow, skc, 64, v0);
      lds_w8(Ash, srow, skc + 8, 64, v1);
    }
    const unsigned short* bs = Bt + (long)(bn + srow) * Ktot + gk;
    lds_w8(Bsh, srow, skc,     64, *(const bf16x8*)bs);
    lds_w8(Bsh, srow, skc + 8, 64, *(const bf16x8*)(bs + 8));
    __syncthreads();
    #pragma unroll
    for (int ks = 0; ks < 2; ks++){
      int kb = ks*32 + khalf*8;
      bf16x8 a0 = lds_r8(Ash, wr*32 +      r16, kb, 64);
      bf16x8 a1 = lds_r8(Ash, wr*32 + 16 + r16, kb, 64);
      bf16x8 b0 = lds_r8(Bsh, wc*32 +      r16, kb, 64);
      bf16x8 b1 = lds_r8(Bsh, wc*32 + 16 + r16, kb, 64);
      acc00 = mfma16(a0, b0, acc00);
      acc01 = mfma16(a0, b1, acc01);
      acc10 = mfma16(a1, b0, acc10);
      acc11 = mfma16(a1, b1, acc11);
    }
    __syncthreads();
  }
  #pragma unroll
  for (int r = 0; r < 4; r++){
    int mA = bm + wr*32 +      khalf*4 + r;
    int mB = bm + wr*32 + 16 + khalf*4 + r;
    int nA = bn + wc*32 +      r16;
    int nB = bn + wc*32 + 16 + r16;
    float v00 = acc00[r] + bias[nA]; float v01 = acc01[r] + bias[nB];
    float v10 = acc10[r] + bias[nA]; float v11 = acc11[r] + bias[nB];
    if (RELU){ v00 = fmaxf(v00,0.f); v01 = fmaxf(v01,0.f); v10 = fmaxf(v10,0.f); v11 = fmaxf(v11,0.f); }
    if (OUTBF16){
      unsigned short* C = (unsigned short*)Cp;
      C[(long)mA*N + nA] = f2bf(v00); C[(long)mA*N + nB] = f2bf(v01);
      C[(long)mB*N + nA] = f2bf(v10); C[(long)mB*N + nB] = f2bf(v11);
    } else {
      float* C = (float*)Cp;
      C[(long)mA*N + nA] = v00; C[(long)mA*N + nB] = v01;
      C[(long)mB*N + nA] = v10; C[(long)mB*N + nB] = v11;
    }
  }
}

// ---------------- similarity GEMM + fused per-chunk top-24 -------------------
// 256 blocks: chunk = bid&7 (XCD-affine), rowtile = bid>>3. 64 query rows x
// 12500-col chunk. Q in registers; corpus via double-buffered global_load_lds
// (inverse-swizzled source). Top-24 per row in OWNER-LANE REGISTERS
// (wave w owns rows 16w..16w+15 on lanes 0..15) with two-level early-out.
__global__ __launch_bounds__(256, 1) void k_sim_topk(
    const unsigned short* __restrict__ Qb, const unsigned short* __restrict__ Cb,
    float* __restrict__ candS, int* __restrict__ candI)
{
  __shared__ unsigned short Csh[2][64*512];  // 2 x 64KB
  __shared__ float scS[64*64];               // swizzled score tile
  int bid = blockIdx.x;
  int chunk = bid & 7, rowtile = bid >> 3;
  int t = threadIdx.x, lane = t & 63, wid = t >> 6;
  int wr = wid >> 1, wc = wid & 1;
  int r16 = lane & 15, khalf = lane >> 4;
  int jb0 = chunk * CHUNK;
  int jend = jb0 + CHUNK;                    // 8*12500 == N_, always valid
  const int njt = (CHUNK + 63) / 64;         // 196

  // Q fragments -> registers: 2 row-tiles x 16 k-steps (K=32 each)
  bf16x8 areg[2][16];
  {
    const unsigned short* qb = Qb + ((long)(rowtile*64 + wr*32) << 9);
    #pragma unroll
    for (int mt = 0; mt < 2; mt++)
      #pragma unroll
      for (int ks = 0; ks < 16; ks++)
        areg[mt][ks] = *(const bf16x8*)(qb + ((long)(mt*16 + r16) << 9) + ks*32 + khalf*8);
  }

  // register top-24 (owner lanes only use it; allocated in all)
  float ts[TOPC]; int ti[TOPC];
  #pragma unroll
  for (int q = 0; q < TOPC; q++){ ts[q] = -__builtin_inff(); ti[q] = 0; }
  float rmin = -__builtin_inff();

  // stage one 64-row corpus tile into Csh[buf] via global_load_lds.
  // LDS dest is linear (row*1KB + lane*16); source byte pre-XORed so LDS
  // content matches the lds_r8 swizzle. Clamp j (selection guard filters).
  auto stage = [&](int buf, int jt){
    const char* cbase = (const char*)Cb;
    char* lbase = (char*)&Csh[buf][0];
    int xo = lane * 16;
    #pragma unroll
    for (int i = 0; i < 16; i++){
      int r = (wid << 4) + i;
      int j = jb0 + (jt << 6) + r;
      int jc = (j < N_) ? j : (N_ - 1);
      const char* src = cbase + ((long)jc << 10) + (xo ^ ((r & 7) << 4));
      gload_lds16(src, lbase + (r << 10));
    }
  };

  stage(0, 0);
  __syncthreads();

  for (int jt = 0; jt < njt; jt++){
    int cur = jt & 1;
    if (jt + 1 < njt) stage(cur ^ 1, jt + 1);   // DMA flies under MFMA phase

    f32x4 acc00 = {0,0,0,0}, acc01 = {0,0,0,0}, acc10 = {0,0,0,0}, acc11 = {0,0,0,0};
    const unsigned short* cbuf = Csh[cur];
    #pragma unroll
    for (int ks = 0; ks < 16; ks++){
      int kb = ks*32 + khalf*8;
      bf16x8 b0 = lds_r8(cbuf, wc*32 +      r16, kb, 512);
      bf16x8 b1 = lds_r8(cbuf, wc*32 + 16 + r16, kb, 512);
      acc00 = mfma16(areg[0][ks], b0, acc00);
      acc01 = mfma16(areg[0][ks], b1, acc01);
      acc10 = mfma16(areg[1][ks], b0, acc10);
      acc11 = mfma16(areg[1][ks], b1, acc11);
    }
    #pragma unroll
    for (int r = 0; r < 4; r++){
      scS[sc_idx(wr*32 +      khalf*4 + r, wc*32 +      r16)] = acc00[r];
      scS[sc_idx(wr*32 +      khalf*4 + r, wc*32 + 16 + r16)] = acc01[r];
      scS[sc_idx(wr*32 + 16 + khalf*4 + r, wc*32 +      r16)] = acc10[r];
      scS[sc_idx(wr*32 + 16 + khalf*4 + r, wc*32 + 16 + r16)] = acc11[r];
    }
    __syncthreads();

    // selection scan: lane<16 of each wave owns row wid*16+lane
    if (lane < 16){
      int row = (wid << 4) + lane;
      float m = -__builtin_inff();
      #pragma unroll
      for (int qd = 0; qd < 16; qd++){
        f32x4 v = *(const f32x4*)&scS[sc_idx(row, qd*4)];
        m = fmaxf(m, fmaxf(fmaxf(v[0], v[1]), fmaxf(v[2], v[3])));
      }
      if (m > rmin){
        int jb = jb0 + (jt << 6);
        #pragma unroll
        for (int qd = 0; qd < 16; qd++){
          f32x4 v = *(const f32x4*)&scS[sc_idx(row, qd*4)];
          float qm = fmaxf(fmaxf(v[0], v[1]), fmaxf(v[2], v[3]));
          if (qm > rmin){
            #pragma unroll
            for (int u = 0; u < 4; u++){
              float s = v[u]; int j = jb + qd*4 + u;
              if (s > rmin && j < jend){
                // replace current min slot (all-register, unrolled)
                float mn = ts[0]; int msl = 0;
                #pragma unroll
                for (int q = 1; q < TOPC; q++){
                  bool lt = ts[q] < mn;
                  mn = lt ? ts[q] : mn; msl = lt ? q : msl;
                }
                #pragma unroll
                for (int q = 0; q < TOPC; q++) if (q == msl){ ts[q] = s; ti[q] = j; }
                float nm = ts[0];
                #pragma unroll
                for (int q = 1; q < TOPC; q++) nm = fminf(nm, ts[q]);
                rmin = nm;
              }
            }
          }
        }
      }
    }
    __syncthreads();
  }

  if (lane < 16){
    int row = (wid << 4) + lane;
    long o = (((long)(rowtile*64 + row)) * NCHUNK + chunk) * TOPC;
    #pragma unroll
    for (int q = 0; q < TOPC; q++){ candS[o+q] = ts[q]; candI[o+q] = ti[q]; }
  }
}

// ---------------- merge 192 candidates -> top-48 -> fp64 rescore -> top-16 ---
__global__ __launch_bounds__(256) void k_finalize(
    const float* __restrict__ candS, const int* __restrict__ candI,
    const float* __restrict__ contrast, const float* __restrict__ corpus,
    float* __restrict__ outScore, float* __restrict__ outIdxF, int* __restrict__ outIdxI)
{
  __shared__ float cs[NCAND];
  __shared__ int   ci[NCAND];
  __shared__ float q[E_];
  __shared__ float wS[4]; __shared__ int wP[4];
  __shared__ double wD[4];
  __shared__ int sel[NSEL];
  __shared__ double exS[NSEL];
  __shared__ double qn_sh;
  int row = blockIdx.x, t = threadIdx.x, lane = t & 63, wid = t >> 6;

  for (int i = t; i < NCAND; i += 256){ cs[i] = candS[(long)row*NCAND + i]; ci[i] = candI[(long)row*NCAND + i]; }
  for (int i = t; i < E_; i += 256) q[i] = contrast[(long)row*E_ + i];
  __syncthreads();

  double qs = 0.0;
  for (int i = t; i < E_; i += 256){ double v = q[i]; qs += v*v; }
  #pragma unroll
  for (int o = 32; o; o >>= 1) qs += __shfl_xor(qs, o, 64);
  if (lane == 0) wD[wid] = qs;
  __syncthreads();
  if (t == 0) qn_sh = fmax(sqrt(wD[0]+wD[1]+wD[2]+wD[3]), 1e-12);
  __syncthreads();

  for (int it = 0; it < NSEL; it++){
    float bs = -__builtin_inff(); int bp = -1;
    for (int i = t; i < NCAND; i += 256){
      float s = cs[i];
      if (s > bs || (s == bs && bp >= 0 && ci[i] < ci[bp])){ bs = s; bp = i; }
    }
    #pragma unroll
    for (int o = 32; o; o >>= 1){
      float os = __shfl_xor(bs, o, 64);
      int   op = __shfl_xor(bp, o, 64);
      bool take = false;
      if (op >= 0){
        if (os > bs) take = true;
        else if (os == bs && (bp < 0 || ci[op] < ci[bp])) take = true;
      }
      if (take){ bs = os; bp = op; }
    }
    if (lane == 0){ wS[wid] = bs; wP[wid] = bp; }
    __syncthreads();
    if (t == 0){
      float s = -__builtin_inff(); int p = -1;
      for (int w = 0; w < 4; w++){
        float os = wS[w]; int op = wP[w];
        if (op >= 0 && (os > s || (os == s && (p < 0 || ci[op] < ci[p])))){ s = os; p = op; }
      }
      sel[it] = (p >= 0) ? ci[p] : 0;
      if (p >= 0) cs[p] = -__builtin_inff();
    }
    __syncthreads();
  }

  for (int c = wid; c < NSEL; c += 4){
    int j = sel[c];
    const float* cr = corpus + ((long)j << 9);
    int e = lane * 8;
    f32x4 v1 = *(const f32x4*)(cr + e);
    f32x4 v2 = *(const f32x4*)(cr + e + 4);
    f32x4 q1 = *(const f32x4*)(&q[e]);
    f32x4 q2 = *(const f32x4*)(&q[e+4]);
    double ds = 0.0, dn = 0.0;
    #pragma unroll
    for (int u = 0; u < 4; u++){ ds += (double)v1[u]*(double)q1[u]; dn += (double)v1[u]*(double)v1[u]; }
    #pragma unroll
    for (int u = 0; u < 4; u++){ ds += (double)v2[u]*(double)q2[u]; dn += (double)v2[u]*(double)v2[u]; }
    #pragma unroll
    for (int o = 32; o; o >>= 1){ ds += __shfl_xor(ds, o, 64); dn += __shfl_xor(dn, o, 64); }
    if (lane == 0) exS[c] = ds / (fmax(sqrt(dn), 1e-12) * qn_sh);
  }
  __syncthreads();

  if (t == 0){
    double bsv[KTOP]; int biv[KTOP];
    #pragma unroll
    for (int i = 0; i < KTOP; i++){ bsv[i] = -__builtin_inf(); biv[i] = 0x7fffffff; }
    for (int c = 0; c < NSEL; c++){
      double s = exS[c]; int j = sel[c];
      int pos = KTOP;
      for (int i = 0; i < KTOP; i++){
        if (s > bsv[i] || (s == bsv[i] && j < biv[i])){ pos = i; break; }
      }
      if (pos < KTOP){
        for (int i = KTOP-1; i > pos; i--){ bsv[i] = bsv[i-1]; biv[i] = biv[i-1]; }
        bsv[pos] = s; biv[pos] = j;
      }
    }
    for (int i = 0; i < KTOP; i++){
      outScore[(long)row*KTOP + i] = (float)bsv[i];
      outIdxF [(long)row*KTOP + i] = (float)biv[i];
      outIdxI [(long)row*KTOP + i] = biv[i];
    }
  }
}

// ---------------- gather retrieved corpus rows (un-normalized) -> bf16 -------
__global__ void k_gather_bf16(const float* __restrict__ corpus, const int* __restrict__ topidx,
                              unsigned short* __restrict__ out){
  int row = blockIdx.x, t = threadIdx.x;
  #pragma unroll
  for (int seg = 0; seg < KTOP; seg++){
    int j = topidx[row*KTOP + seg];
    const float* src = corpus + ((long)j << 9);
    unsigned short* dst = out + ((long)row << 13) + (seg << 9);
    int e = t * 2;
    f32x2 v = *(const f32x2*)(src + e);
    dst[e] = f2bf(v[0]); dst[e+1] = f2bf(v[1]);
  }
}

// ---------------- final gemv: outcome = z2 @ op_w3 + b3 ----------------
__global__ void k_gemv_out(const float* __restrict__ z2, const float* __restrict__ w3,
                           const float* __restrict__ b3, float* __restrict__ outc){
  int gw = (blockIdx.x * 256 + threadIdx.x) >> 6, lane = threadIdx.x & 63;
  if (gw >= B_) return;
  const float* r = z2 + (long)gw * 512;
  int e = lane * 8;
  f32x4 a1 = *(const f32x4*)(r + e),  a2 = *(const f32x4*)(r + e + 4);
  f32x4 b1 = *(const f32x4*)(w3 + e), b2 = *(const f32x4*)(w3 + e + 4);
  float s = a1[0]*b1[0]+a1[1]*b1[1]+a1[2]*b1[2]+a1[3]*b1[3]
          + a2[0]*b2[0]+a2[1]*b2[1]+a2[2]*b2[2]+a2[3]*b2[3];
  #pragma unroll
  for (int o = 32; o; o >>= 1) s += __shfl_xor(s, o, 64);
  if (lane == 0) outc[gw] = s + b3[0];
}

extern "C" void kernel_launch(void* const* d_in, const int* in_sizes, int n_in,
                              void* d_out, int out_size, void* d_ws, size_t ws_size,
                              hipStream_t stream)
{
  (void)in_sizes; (void)n_in; (void)out_size; (void)ws_size;
  const float* patient     = (const float*)d_in[0];
  const float* treatment   = (const float*)d_in[1];
  const float* confounders = (const float*)d_in[2];
  const float* corpus      = (const float*)d_in[3];
  const float* pe_w1 = (const float*)d_in[4];  const float* pe_b1 = (const float*)d_in[5];
  const float* pe_w2 = (const float*)d_in[6];  const float* pe_b2 = (const float*)d_in[7];
  const float* te_w  = (const float*)d_in[8];  const float* te_b  = (const float*)d_in[9];
  const float* ce_w  = (const float*)d_in[10]; const float* ce_b  = (const float*)d_in[11];
  const float* co_w1 = (const float*)d_in[12]; const float* co_b1 = (const float*)d_in[13];
  const float* co_w2 = (const float*)d_in[14]; const float* co_b2 = (const float*)d_in[15];
  const float* re_w  = (const float*)d_in[16]; const float* re_b  = (const float*)d_in[17];
  const float* op_w1 = (const float*)d_in[18]; const float* op_b1 = (const float*)d_in[19];
  const float* op_w2 = (const float*)d_in[20]; const float* op_b2 = (const float*)d_in[21];
  const float* op_w3 = (const float*)d_in[22]; const float* op_b3 = (const float*)d_in[23];

  float* out = (float*)d_out;
  float* out_outcome = out;
  float* out_scores  = out + 2048;
  float* out_idxf    = out + 2048 + 32768;
  float* out_contr   = out + 2048 + 32768 + 32768;

  char* ws = (char*)d_ws;
  const size_t MB = 1024*1024;
  unsigned short* cb    = (unsigned short*)(ws + 0);        // 97.7 MB (corpus bf16)
  unsigned short* retr  = (unsigned short*)(ws + 0);        // 32 MB (after sim)
  unsigned short* reT   = (unsigned short*)(ws + 34*MB);    // 16 MB
  unsigned short* op1T  = (unsigned short*)(ws + 51*MB);    // 6.3 MB
  unsigned short* op2T  = (unsigned short*)(ws + 58*MB);    // 1 MB
  float* t2     = (float*)(ws + 60*MB);                     // 8 MB (dead before re_out)
  float* re_out = (float*)(ws + 60*MB);                     // 8 MB
  unsigned short* z1 = (unsigned short*)(ws + 69*MB);       // 4 MB
  float* z2     = (float*)(ws + 74*MB);                     // 4 MB
  float* te_emb = (float*)(ws + 98*MB);                     // 8 MB persist
  float* ce_emb = (float*)(ws + 107*MB);                    // 8 MB persist
  float* t1     = (float*)(ws + 116*MB);                    // 8 MB (phase A)
  float* pe_emb = (float*)(ws + 125*MB);                    // 8 MB (phase A)
  unsigned short* qb = (unsigned short*)(ws + 116*MB);      // 2 MB (phase B, t1 dead)
  float* candS = (float*)(ws + 121*MB);                     // 1.5 MB
  int*   candI = (int*)(ws + 127*MB);                       // 1.5 MB
  int*   topidx= (int*)(ws + 133*MB);                       // 128 KB

  dim3 blk(256);
  // --- encoders (fp32, query-precision-critical) ---
  k_gemm_f32<1,true ><<<dim3(16,16), blk, 0, stream>>>(patient, 320, nullptr, 0, pe_w1, pe_b1, t1, 1024, 320);
  k_gemm_f32<1,false><<<dim3(16,16), blk, 0, stream>>>(t1, 1024, nullptr, 0, pe_w2, pe_b2, pe_emb, 1024, 1024);
  k_gemm_f32<1,false><<<dim3(16,16), blk, 0, stream>>>(treatment, 64, nullptr, 0, te_w, te_b, te_emb, 1024, 64);
  k_gemm_f32<1,false><<<dim3(16,16), blk, 0, stream>>>(confounders, 256, nullptr, 0, ce_w, ce_b, ce_emb, 1024, 256);
  k_gemm_f32<2,true ><<<dim3(16,16), blk, 0, stream>>>(pe_emb, 1024, ce_emb, 1024, co_w1, co_b1, t2, 1024, 2048);
  k_gemm_f32<1,false><<<dim3(16, 8), blk, 0, stream>>>(t2, 1024, nullptr, 0, co_w2, co_b2, out_contr, 512, 1024);
  // --- fused normalize + bf16 convert ---
  k_norm_bf16<<<dim3(512),   blk, 0, stream>>>(out_contr, qb, 2048);
  k_norm_bf16<<<dim3(25000), blk, 0, stream>>>(corpus, cb, 100000);
  // --- similarity + top-k ---
  k_sim_topk<<<dim3(256), blk, 0, stream>>>(qb, cb, candS, candI);
  k_finalize<<<dim3(2048), blk, 0, stream>>>(candS, candI, out_contr, corpus, out_scores, out_idxf, topidx);
  // --- retrieval encoder + outcome head (bf16 MFMA) ---
  k_gather_bf16<<<dim3(2048), blk, 0, stream>>>(corpus, topidx, retr);
  k_transpose_bf16<<<dim3(256,32), blk, 0, stream>>>(re_w,  reT,  8192, 1024);
  k_transpose_bf16<<<dim3(96,32),  blk, 0, stream>>>(op_w1, op1T, 3072, 1024);
  k_transpose_bf16<<<dim3(32,16),  blk, 0, stream>>>(op_w2, op2T, 1024, 512);
  k_gemm_bf16<1,false,false,false><<<dim3(32,16), blk, 0, stream>>>(retr, 8192, nullptr, 0, nullptr, reT, re_b, re_out, 1024, 8192);
  k_gemm_bf16<3,true, true, true ><<<dim3(32,16), blk, 0, stream>>>(te_emb, 1024, ce_emb, 1024, re_out, op1T, op_b1, z1, 1024, 3072);
  k_gemm_bf16<1,false,true, false><<<dim3(32, 8), blk, 0, stream>>>(z1, 1024, nullptr, 0, nullptr, op2T, op_b2, z2, 512, 1024);
  k_gemv_out<<<dim3(512), blk, 0, stream>>>(z2, op_w3, op_b3, out_outcome);
}

// Round 3
// 1433.537 us; speedup vs baseline: 2.6891x; 1.7303x over previous
//
#include <hip/hip_runtime.h>
#include <math.h>

#define DEV static __device__ __forceinline__

typedef __attribute__((ext_vector_type(4))) float f32x4;
typedef __attribute__((ext_vector_type(2))) float f32x2;
typedef __attribute__((ext_vector_type(8))) short bf16x8;

#define B_    2048
#define N_    100000
#define E_    512
#define KTOP  16
#define CHUNK 6250
#define NCHUNK 16
#define TOPH  12                      /* top-12 per (chunk, col-half) */
#define NCAND (NCHUNK*2*TOPH)         /* 384 per row */
#define NSEL  48
#define NEGINF (-__builtin_inff())

DEV unsigned short f2bf(float f){
  union { float f; unsigned u; } v; v.f = f;
  unsigned r = v.u + 0x7fffu + ((v.u >> 16) & 1u);
  return (unsigned short)(r >> 16);
}

DEV f32x4 mfma16(bf16x8 a, bf16x8 b, f32x4 c){
  return __builtin_amdgcn_mfma_f32_16x16x32_bf16(a, b, c, 0, 0, 0);
}

// swizzled LDS helpers for bf16 tiles (byte ^= (row&7)<<4)
DEV void lds_w8(unsigned short* base, int row, int k, int stride, bf16x8 v){
  char* p = (char*)base + (((row*stride + k)*2) ^ ((row & 7) << 4));
  *(bf16x8*)p = v;
}
DEV bf16x8 lds_r8(const unsigned short* base, int row, int k, int stride){
  const char* p = (const char*)base + (((row*stride + k)*2) ^ ((row & 7) << 4));
  return *(const bf16x8*)p;
}

// global -> LDS direct DMA, 16B per lane.
DEV void gload_lds16(const void* g, void* l){
  __builtin_amdgcn_global_load_lds(
      (const __attribute__((address_space(1))) void*)(unsigned long long)(uintptr_t)g,
      (__attribute__((address_space(3))) void*)(unsigned)(uintptr_t)l,
      16, 0, 0);
}

// score-tile swizzle: word = (row*64+col) ^ ((row&15)<<2). Bits 0-1 of col
// untouched -> f32x4 at col%4==0 stays contiguous/aligned; 16 distinct
// 16B-slots per col-quad across rows -> ~2-way (free) on scan reads.
DEV int sc2_idx(int row, int col){ return ((row << 6) | col) ^ ((row & 15) << 2); }

// ---------------- fused row L2-normalize + bf16 convert (1 wave / row) -------
__global__ void k_norm_bf16(const float* __restrict__ x, unsigned short* __restrict__ out, int rows){
  int gw = (blockIdx.x * 256 + threadIdx.x) >> 6;
  int lane = threadIdx.x & 63;
  if (gw >= rows) return;
  const float* r = x + (long)gw * E_;
  f32x4 v0 = *(const f32x4*)(r + lane*8);
  f32x4 v1 = *(const f32x4*)(r + lane*8 + 4);
  float s = v0[0]*v0[0]+v0[1]*v0[1]+v0[2]*v0[2]+v0[3]*v0[3]
          + v1[0]*v1[0]+v1[1]*v1[1]+v1[2]*v1[2]+v1[3]*v1[3];
  #pragma unroll
  for (int o = 32; o; o >>= 1) s += __shfl_xor(s, o, 64);
  float inv = 1.f / fmaxf(sqrtf(s), 1e-12f);
  bf16x8 o;
  o[0]=(short)f2bf(v0[0]*inv); o[1]=(short)f2bf(v0[1]*inv); o[2]=(short)f2bf(v0[2]*inv); o[3]=(short)f2bf(v0[3]*inv);
  o[4]=(short)f2bf(v1[0]*inv); o[5]=(short)f2bf(v1[1]*inv); o[6]=(short)f2bf(v1[2]*inv); o[7]=(short)f2bf(v1[3]*inv);
  *(bf16x8*)(out + (long)gw*E_ + lane*8) = o;
}

// ---------------- fp32 GEMM (encoders): C = act(A @ W + b), W is [K,N] ------
template<int NSEG, bool RELU>
__global__ __launch_bounds__(256) void k_gemm_f32(
    const float* __restrict__ A0, int K0,
    const float* __restrict__ A1, int K1,
    const float* __restrict__ Bw, const float* __restrict__ bias,
    float* __restrict__ C, int N, int Ktot)
{
  __shared__ float At[16][132];   // [k][m]
  __shared__ float Bt[16][68];    // [k][n]
  int bm = blockIdx.x * 128, bn = blockIdx.y * 64;
  int t = threadIdx.x;
  int tx = t & 15, ty = t >> 4;
  int ar = t >> 1, ac = (t & 1) * 8;
  float acc[8][4] = {};
  for (int k0 = 0; k0 < Ktot; k0 += 16){
    {
      int gk = k0 + ac;
      const float* src = A0; int kk = gk, ld = K0;
      if (NSEG == 2 && gk >= K0){ src = A1; kk = gk - K0; ld = K1; }
      const float* p = src + (long)(bm + ar) * ld + kk;
      f32x4 v0 = *(const f32x4*)p;
      f32x4 v1 = *(const f32x4*)(p + 4);
      #pragma unroll
      for (int i = 0; i < 4; i++) At[ac+i][ar] = v0[i];
      #pragma unroll
      for (int i = 0; i < 4; i++) At[ac+4+i][ar] = v1[i];
    }
    *(f32x4*)&Bt[ty][tx*4] = *(const f32x4*)(Bw + (long)(k0 + ty) * N + bn + tx*4);
    __syncthreads();
    #pragma unroll
    for (int k = 0; k < 16; k++){
      f32x4 a0 = *(const f32x4*)&At[k][ty*8];
      f32x4 a1 = *(const f32x4*)&At[k][ty*8+4];
      f32x4 b  = *(const f32x4*)&Bt[k][tx*4];
      #pragma unroll
      for (int i = 0; i < 4; i++){
        #pragma unroll
        for (int j = 0; j < 4; j++){ acc[i][j] += a0[i]*b[j]; acc[4+i][j] += a1[i]*b[j]; }
      }
    }
    __syncthreads();
  }
  f32x4 bi = *(const f32x4*)(bias + bn + tx*4);
  #pragma unroll
  for (int i = 0; i < 8; i++){
    int m = bm + ty*8 + i;
    f32x4 v;
    #pragma unroll
    for (int j = 0; j < 4; j++){
      float x = acc[i][j] + bi[j];
      v[j] = RELU ? fmaxf(x, 0.f) : x;
    }
    *(f32x4*)(C + (long)m*N + bn + tx*4) = v;
  }
}

// ---------------- transpose fp32 [K,N] -> bf16 [N,K] ----------------
__global__ void k_transpose_bf16(const float* __restrict__ W, unsigned short* __restrict__ WT, int K, int N){
  __shared__ float tile[32][33];
  int k0 = blockIdx.x * 32, n0 = blockIdx.y * 32;
  int tx = threadIdx.x & 31, ty = threadIdx.x >> 5;
  #pragma unroll
  for (int r = 0; r < 32; r += 8) tile[ty + r][tx] = W[(long)(k0 + ty + r) * N + n0 + tx];
  __syncthreads();
  #pragma unroll
  for (int r = 0; r < 32; r += 8) WT[(long)(n0 + ty + r) * K + k0 + tx] = f2bf(tile[tx][ty + r]);
}

// ---------------- bf16 MFMA NT GEMM: C = act(A @ Bt^T + bias) ----------------
template<int NSEG, bool AF32, bool RELU, bool OUTBF16>
__global__ __launch_bounds__(256) void k_gemm_bf16(
    const void* __restrict__ A0p, int K0,
    const void* __restrict__ A1p, int K1,
    const void* __restrict__ A2p,
    const unsigned short* __restrict__ Bt, const float* __restrict__ bias,
    void* __restrict__ Cp, int N, int Ktot)
{
  __shared__ unsigned short Ash[64*64];
  __shared__ unsigned short Bsh[64*64];
  int bm = blockIdx.x * 64, bn = blockIdx.y * 64;
  int t = threadIdx.x, lane = t & 63, wid = t >> 6;
  int wr = wid >> 1, wc = wid & 1;
  int r16 = lane & 15, khalf = lane >> 4;
  int srow = t >> 2, skc = (t & 3) * 16;
  f32x4 acc00 = {0,0,0,0}, acc01 = {0,0,0,0}, acc10 = {0,0,0,0}, acc11 = {0,0,0,0};

  for (int k0 = 0; k0 < Ktot; k0 += 64){
    int gk = k0 + skc;
    if (!AF32){
      const unsigned short* A = (const unsigned short*)A0p;
      const unsigned short* s = A + (long)(bm + srow) * Ktot + gk;
      lds_w8(Ash, srow, skc,     64, *(const bf16x8*)s);
      lds_w8(Ash, srow, skc + 8, 64, *(const bf16x8*)(s + 8));
    } else {
      const float* s; int kk, ld;
      if (NSEG >= 2 && gk >= K0){
        if (NSEG == 3 && gk >= K0 + K1){ s = (const float*)A2p; kk = gk - K0 - K1; ld = Ktot - K0 - K1; }
        else                           { s = (const float*)A1p; kk = gk - K0;      ld = K1; }
      } else { s = (const float*)A0p; kk = gk; ld = K0; }
      const float* p = s + (long)(bm + srow) * ld + kk;
      f32x4 f0 = *(const f32x4*)p, f1 = *(const f32x4*)(p+4), f2 = *(const f32x4*)(p+8), f3 = *(const f32x4*)(p+12);
      bf16x8 v0, v1;
      v0[0]=(short)f2bf(f0[0]); v0[1]=(short)f2bf(f0[1]); v0[2]=(short)f2bf(f0[2]); v0[3]=(short)f2bf(f0[3]);
      v0[4]=(short)f2bf(f1[0]); v0[5]=(short)f2bf(f1[1]); v0[6]=(short)f2bf(f1[2]); v0[7]=(short)f2bf(f1[3]);
      v1[0]=(short)f2bf(f2[0]); v1[1]=(short)f2bf(f2[1]); v1[2]=(short)f2bf(f2[2]); v1[3]=(short)f2bf(f2[3]);
      v1[4]=(short)f2bf(f3[0]); v1[5]=(short)f2bf(f3[1]); v1[6]=(short)f2bf(f3[2]); v1[7]=(short)f2bf(f3[3]);
      lds_w8(Ash, srow, skc, 64, v0);
      lds_w8(Ash, srow, skc + 8, 64, v1);
    }
    const unsigned short* bs = Bt + (long)(bn + srow) * Ktot + gk;
    lds_w8(Bsh, srow, skc,     64, *(const bf16x8*)bs);
    lds_w8(Bsh, srow, skc + 8, 64, *(const bf16x8*)(bs + 8));
    __syncthreads();
    #pragma unroll
    for (int ks = 0; ks < 2; ks++){
      int kb = ks*32 + khalf*8;
      bf16x8 a0 = lds_r8(Ash, wr*32 +      r16, kb, 64);
      bf16x8 a1 = lds_r8(Ash, wr*32 + 16 + r16, kb, 64);
      bf16x8 b0 = lds_r8(Bsh, wc*32 +      r16, kb, 64);
      bf16x8 b1 = lds_r8(Bsh, wc*32 + 16 + r16, kb, 64);
      acc00 = mfma16(a0, b0, acc00);
      acc01 = mfma16(a0, b1, acc01);
      acc10 = mfma16(a1, b0, acc10);
      acc11 = mfma16(a1, b1, acc11);
    }
    __syncthreads();
  }
  #pragma unroll
  for (int r = 0; r < 4; r++){
    int mA = bm + wr*32 +      khalf*4 + r;
    int mB = bm + wr*32 + 16 + khalf*4 + r;
    int nA = bn + wc*32 +      r16;
    int nB = bn + wc*32 + 16 + r16;
    float v00 = acc00[r] + bias[nA]; float v01 = acc01[r] + bias[nB];
    float v10 = acc10[r] + bias[nA]; float v11 = acc11[r] + bias[nB];
    if (RELU){ v00 = fmaxf(v00,0.f); v01 = fmaxf(v01,0.f); v10 = fmaxf(v10,0.f); v11 = fmaxf(v11,0.f); }
    if (OUTBF16){
      unsigned short* C = (unsigned short*)Cp;
      C[(long)mA*N + nA] = f2bf(v00); C[(long)mA*N + nB] = f2bf(v01);
      C[(long)mB*N + nA] = f2bf(v10); C[(long)mB*N + nB] = f2bf(v11);
    } else {
      float* C = (float*)Cp;
      C[(long)mA*N + nA] = v00; C[(long)mA*N + nB] = v01;
      C[(long)mB*N + nA] = v10; C[(long)mB*N + nB] = v11;
    }
  }
}

// ---------------- similarity GEMM + fused top-12 per (chunk, col-half) -------
// 256 blocks = 16 rowtiles x 16 chunks; chunk=(bid&7)*2+(bid>>7) pins each
// chunk's 16 blocks to one XCD (L2 reuse). 128 query rows/block, Q fully in
// registers (256 VGPR; 1 wave/SIMD anyway due to 160KB LDS). Corpus double-
// buffered via global_load_lds. Selection: 1 col-half-row per lane, top-12 in
// registers, wave-uniform extraction rounds (argmax -> replace-min -> mask).
__global__ __launch_bounds__(256, 1) void k_sim_topk(
    const unsigned short* __restrict__ Qb, const unsigned short* __restrict__ Cb,
    float* __restrict__ candS, int* __restrict__ candI)
{
  __shared__ unsigned short Csh[2][64*512];  // 2 x 64KB corpus tiles
  __shared__ float scS[128*64];              // 32KB swizzled score tile
  int bid = blockIdx.x;
  int chunk = ((bid & 7) << 1) | (bid >> 7);
  int rowtile = (bid & 127) >> 3;
  int t = threadIdx.x, lane = t & 63, wid = t >> 6;
  int wr = wid >> 1, wc = wid & 1;
  int r16 = lane & 15, khalf = lane >> 4;
  int jb0 = chunk * CHUNK;
  int jendc = jb0 + CHUNK;
  const int njt = (CHUNK + 63) >> 6;         // 98

  // Q fragments -> registers: 4 row-tiles x 16 k-steps
  bf16x8 areg[4][16];
  {
    const unsigned short* qb = Qb + ((long)(rowtile*128 + wr*64) << 9);
    #pragma unroll
    for (int mt = 0; mt < 4; mt++)
      #pragma unroll
      for (int ks = 0; ks < 16; ks++)
        areg[mt][ks] = *(const bf16x8*)(qb + ((long)(mt*16 + r16) << 9) + ks*32 + khalf*8);
  }

  float ts[TOPH]; int ti[TOPH];
  #pragma unroll
  for (int q = 0; q < TOPH; q++){ ts[q] = NEGINF; ti[q] = 0; }
  float rmin = NEGINF;
  int selrow = t & 127, hb = (t >> 7) << 5;  // owned row + col-half base

  auto stage = [&](int buf, int jt){
    const char* cbase = (const char*)Cb;
    char* lbase = (char*)&Csh[buf][0];
    int xo = lane * 16;
    #pragma unroll
    for (int i = 0; i < 16; i++){
      int r = (wid << 4) + i;
      int j = jb0 + (jt << 6) + r;
      int jc = (j < N_) ? j : (N_ - 1);
      const char* src = cbase + ((long)jc << 10) + (xo ^ ((r & 7) << 4));
      gload_lds16(src, lbase + (r << 10));
    }
  };

  stage(0, 0);
  __syncthreads();

  for (int jt = 0; jt < njt; jt++){
    int cur = jt & 1;
    if (jt + 1 < njt) stage(cur ^ 1, jt + 1);   // DMA flies under MFMA phase

    f32x4 acc[4][2];
    #pragma unroll
    for (int mt = 0; mt < 4; mt++){
      acc[mt][0] = (f32x4){0,0,0,0}; acc[mt][1] = (f32x4){0,0,0,0};
    }
    const unsigned short* cbuf = Csh[cur];
    #pragma unroll
    for (int ks = 0; ks < 16; ks++){
      int kb = ks*32 + khalf*8;
      bf16x8 b0 = lds_r8(cbuf, wc*32 +      r16, kb, 512);
      bf16x8 b1 = lds_r8(cbuf, wc*32 + 16 + r16, kb, 512);
      #pragma unroll
      for (int mt = 0; mt < 4; mt++){
        acc[mt][0] = mfma16(areg[mt][ks], b0, acc[mt][0]);
        acc[mt][1] = mfma16(areg[mt][ks], b1, acc[mt][1]);
      }
    }
    #pragma unroll
    for (int mt = 0; mt < 4; mt++)
      #pragma unroll
      for (int ct = 0; ct < 2; ct++)
        #pragma unroll
        for (int r = 0; r < 4; r++)
          scS[sc2_idx(wr*64 + mt*16 + khalf*4 + r, wc*32 + ct*16 + r16)] = acc[mt][ct][r];
    __syncthreads();

    // ---- selection: lane owns (selrow, col-half hb..hb+31) ----
    {
      int jb = jb0 + (jt << 6);
      f32x4 v[8]; float qm[8];
      #pragma unroll
      for (int q = 0; q < 8; q++)
        v[q] = *(const f32x4*)&scS[sc2_idx(selrow, hb + q*4)];
      int nval = jendc - jb;                   // >= 64 except chunk tail
      if (nval < 64){
        #pragma unroll
        for (int q = 0; q < 8; q++)
          #pragma unroll
          for (int u = 0; u < 4; u++)
            if (hb + q*4 + u >= nval) v[q][u] = NEGINF;
      }
      #pragma unroll
      for (int q = 0; q < 8; q++)
        qm[q] = fmaxf(fmaxf(v[q][0], v[q][1]), fmaxf(v[q][2], v[q][3]));
      float tmax = qm[0];
      #pragma unroll
      for (int q = 1; q < 8; q++) tmax = fmaxf(tmax, qm[q]);

      while (__any(tmax > rmin)){
        bool ins = tmax > rmin;
        // argmax quad
        float bm = qm[0]; int bq = 0;
        #pragma unroll
        for (int q = 1; q < 8; q++){ bool g = qm[q] > bm; bm = g ? qm[q] : bm; bq = g ? q : bq; }
        // select that quad's values (static cndmask chain)
        f32x4 bv = v[0];
        #pragma unroll
        for (int q = 1; q < 8; q++){ bool e = (bq == q); bv = e ? v[q] : bv; }
        // elem argmax
        float em = bv[0]; int bu = 0;
        #pragma unroll
        for (int u = 1; u < 4; u++){ bool g = bv[u] > em; em = g ? bv[u] : em; bu = g ? u : bu; }
        int j = jb + hb + (bq << 2) + bu;
        // replace-min insert (predicated by ins)
        float mn = ts[0]; int ms = 0;
        #pragma unroll
        for (int q = 1; q < TOPH; q++){ bool lt = ts[q] < mn; mn = lt ? ts[q] : mn; ms = lt ? q : ms; }
        #pragma unroll
        for (int q = 0; q < TOPH; q++){
          bool hit = ins && (ms == q);
          ts[q] = hit ? em : ts[q]; ti[q] = hit ? j : ti[q];
        }
        rmin = ts[0];
        #pragma unroll
        for (int q = 1; q < TOPH; q++) rmin = fminf(rmin, ts[q]);
        // mask extracted element, refresh quad maxes
        #pragma unroll
        for (int q = 0; q < 8; q++){
          bool eq = ins && (bq == q);
          #pragma unroll
          for (int u = 0; u < 4; u++){
            bool h = eq && (bu == u);
            v[q][u] = h ? NEGINF : v[q][u];
          }
          qm[q] = fmaxf(fmaxf(v[q][0], v[q][1]), fmaxf(v[q][2], v[q][3]));
        }
        tmax = qm[0];
        #pragma unroll
        for (int q = 1; q < 8; q++) tmax = fmaxf(tmax, qm[q]);
      }
    }
    __syncthreads();
  }

  {
    int grow = rowtile*128 + selrow;
    long o = (((long)grow * NCHUNK + chunk) * 2 + (t >> 7)) * TOPH;
    #pragma unroll
    for (int q = 0; q < TOPH; q++){ candS[o+q] = ts[q]; candI[o+q] = ti[q]; }
  }
}

// ---------------- merge 384 candidates -> top-48 -> fp64 rescore -> top-16 ---
__global__ __launch_bounds__(256) void k_finalize(
    const float* __restrict__ candS, const int* __restrict__ candI,
    const float* __restrict__ contrast, const float* __restrict__ corpus,
    float* __restrict__ outScore, float* __restrict__ outIdxF, int* __restrict__ outIdxI)
{
  __shared__ float cs[NCAND];
  __shared__ int   ci[NCAND];
  __shared__ float q[E_];
  __shared__ float wS[4]; __shared__ int wP[4];
  __shared__ double wD[4];
  __shared__ int sel[NSEL];
  __shared__ double exS[NSEL];
  __shared__ double qn_sh;
  int row = blockIdx.x, t = threadIdx.x, lane = t & 63, wid = t >> 6;

  for (int i = t; i < NCAND; i += 256){ cs[i] = candS[(long)row*NCAND + i]; ci[i] = candI[(long)row*NCAND + i]; }
  for (int i = t; i < E_; i += 256) q[i] = contrast[(long)row*E_ + i];
  __syncthreads();

  double qs = 0.0;
  for (int i = t; i < E_; i += 256){ double v = q[i]; qs += v*v; }
  #pragma unroll
  for (int o = 32; o; o >>= 1) qs += __shfl_xor(qs, o, 64);
  if (lane == 0) wD[wid] = qs;
  __syncthreads();
  if (t == 0) qn_sh = fmax(sqrt(wD[0]+wD[1]+wD[2]+wD[3]), 1e-12);
  __syncthreads();

  for (int it = 0; it < NSEL; it++){
    float bs = NEGINF; int bp = -1;
    for (int i = t; i < NCAND; i += 256){
      float s = cs[i];
      if (s > bs || (s == bs && bp >= 0 && ci[i] < ci[bp])){ bs = s; bp = i; }
    }
    #pragma unroll
    for (int o = 32; o; o >>= 1){
      float os = __shfl_xor(bs, o, 64);
      int   op = __shfl_xor(bp, o, 64);
      bool take = false;
      if (op >= 0){
        if (os > bs) take = true;
        else if (os == bs && (bp < 0 || ci[op] < ci[bp])) take = true;
      }
      if (take){ bs = os; bp = op; }
    }
    if (lane == 0){ wS[wid] = bs; wP[wid] = bp; }
    __syncthreads();
    if (t == 0){
      float s = NEGINF; int p = -1;
      for (int w = 0; w < 4; w++){
        float os = wS[w]; int op = wP[w];
        if (op >= 0 && (os > s || (os == s && (p < 0 || ci[op] < ci[p])))){ s = os; p = op; }
      }
      sel[it] = (p >= 0) ? ci[p] : 0;
      if (p >= 0) cs[p] = NEGINF;
    }
    __syncthreads();
  }

  for (int c = wid; c < NSEL; c += 4){
    int j = sel[c];
    const float* cr = corpus + ((long)j << 9);
    int e = lane * 8;
    f32x4 v1 = *(const f32x4*)(cr + e);
    f32x4 v2 = *(const f32x4*)(cr + e + 4);
    f32x4 q1 = *(const f32x4*)(&q[e]);
    f32x4 q2 = *(const f32x4*)(&q[e+4]);
    double ds = 0.0, dn = 0.0;
    #pragma unroll
    for (int u = 0; u < 4; u++){ ds += (double)v1[u]*(double)q1[u]; dn += (double)v1[u]*(double)v1[u]; }
    #pragma unroll
    for (int u = 0; u < 4; u++){ ds += (double)v2[u]*(double)q2[u]; dn += (double)v2[u]*(double)v2[u]; }
    #pragma unroll
    for (int o = 32; o; o >>= 1){ ds += __shfl_xor(ds, o, 64); dn += __shfl_xor(dn, o, 64); }
    if (lane == 0) exS[c] = ds / (fmax(sqrt(dn), 1e-12) * qn_sh);
  }
  __syncthreads();

  if (t == 0){
    double bsv[KTOP]; int biv[KTOP];
    #pragma unroll
    for (int i = 0; i < KTOP; i++){ bsv[i] = -__builtin_inf(); biv[i] = 0x7fffffff; }
    for (int c = 0; c < NSEL; c++){
      double s = exS[c]; int j = sel[c];
      int pos = KTOP;
      for (int i = 0; i < KTOP; i++){
        if (s > bsv[i] || (s == bsv[i] && j < biv[i])){ pos = i; break; }
      }
      if (pos < KTOP){
        for (int i = KTOP-1; i > pos; i--){ bsv[i] = bsv[i-1]; biv[i] = biv[i-1]; }
        bsv[pos] = s; biv[pos] = j;
      }
    }
    for (int i = 0; i < KTOP; i++){
      outScore[(long)row*KTOP + i] = (float)bsv[i];
      outIdxF [(long)row*KTOP + i] = (float)biv[i];
      outIdxI [(long)row*KTOP + i] = biv[i];
    }
  }
}

// ---------------- gather retrieved corpus rows (un-normalized) -> bf16 -------
__global__ void k_gather_bf16(const float* __restrict__ corpus, const int* __restrict__ topidx,
                              unsigned short* __restrict__ out){
  int row = blockIdx.x, t = threadIdx.x;
  #pragma unroll
  for (int seg = 0; seg < KTOP; seg++){
    int j = topidx[row*KTOP + seg];
    const float* src = corpus + ((long)j << 9);
    unsigned short* dst = out + ((long)row << 13) + (seg << 9);
    int e = t * 2;
    f32x2 v = *(const f32x2*)(src + e);
    dst[e] = f2bf(v[0]); dst[e+1] = f2bf(v[1]);
  }
}

// ---------------- final gemv: outcome = z2 @ op_w3 + b3 ----------------
__global__ void k_gemv_out(const float* __restrict__ z2, const float* __restrict__ w3,
                           const float* __restrict__ b3, float* __restrict__ outc){
  int gw = (blockIdx.x * 256 + threadIdx.x) >> 6, lane = threadIdx.x & 63;
  if (gw >= B_) return;
  const float* r = z2 + (long)gw * 512;
  int e = lane * 8;
  f32x4 a1 = *(const f32x4*)(r + e),  a2 = *(const f32x4*)(r + e + 4);
  f32x4 b1 = *(const f32x4*)(w3 + e), b2 = *(const f32x4*)(w3 + e + 4);
  float s = a1[0]*b1[0]+a1[1]*b1[1]+a1[2]*b1[2]+a1[3]*b1[3]
          + a2[0]*b2[0]+a2[1]*b2[1]+a2[2]*b2[2]+a2[3]*b2[3];
  #pragma unroll
  for (int o = 32; o; o >>= 1) s += __shfl_xor(s, o, 64);
  if (lane == 0) outc[gw] = s + b3[0];
}

extern "C" void kernel_launch(void* const* d_in, const int* in_sizes, int n_in,
                              void* d_out, int out_size, void* d_ws, size_t ws_size,
                              hipStream_t stream)
{
  (void)in_sizes; (void)n_in; (void)out_size; (void)ws_size;
  const float* patient     = (const float*)d_in[0];
  const float* treatment   = (const float*)d_in[1];
  const float* confounders = (const float*)d_in[2];
  const float* corpus      = (const float*)d_in[3];
  const float* pe_w1 = (const float*)d_in[4];  const float* pe_b1 = (const float*)d_in[5];
  const float* pe_w2 = (const float*)d_in[6];  const float* pe_b2 = (const float*)d_in[7];
  const float* te_w  = (const float*)d_in[8];  const float* te_b  = (const float*)d_in[9];
  const float* ce_w  = (const float*)d_in[10]; const float* ce_b  = (const float*)d_in[11];
  const float* co_w1 = (const float*)d_in[12]; const float* co_b1 = (const float*)d_in[13];
  const float* co_w2 = (const float*)d_in[14]; const float* co_b2 = (const float*)d_in[15];
  const float* re_w  = (const float*)d_in[16]; const float* re_b  = (const float*)d_in[17];
  const float* op_w1 = (const float*)d_in[18]; const float* op_b1 = (const float*)d_in[19];
  const float* op_w2 = (const float*)d_in[20]; const float* op_b2 = (const float*)d_in[21];
  const float* op_w3 = (const float*)d_in[22]; const float* op_b3 = (const float*)d_in[23];

  float* out = (float*)d_out;
  float* out_outcome = out;
  float* out_scores  = out + 2048;
  float* out_idxf    = out + 2048 + 32768;
  float* out_contr   = out + 2048 + 32768 + 32768;

  char* ws = (char*)d_ws;
  const size_t MB = 1024*1024;
  unsigned short* cb    = (unsigned short*)(ws + 0);        // 97.7 MB (corpus bf16)
  unsigned short* retr  = (unsigned short*)(ws + 0);        // 32 MB (after sim)
  unsigned short* reT   = (unsigned short*)(ws + 34*MB);    // 16 MB
  unsigned short* op1T  = (unsigned short*)(ws + 51*MB);    // 6.3 MB
  unsigned short* op2T  = (unsigned short*)(ws + 58*MB);    // 1 MB
  float* t2     = (float*)(ws + 60*MB);                     // 8 MB (dead before re_out)
  float* re_out = (float*)(ws + 60*MB);                     // 8 MB
  unsigned short* z1 = (unsigned short*)(ws + 69*MB);       // 4 MB
  float* z2     = (float*)(ws + 74*MB);                     // 4 MB
  float* te_emb = (float*)(ws + 98*MB);                     // 8 MB persist
  float* ce_emb = (float*)(ws + 107*MB);                    // 8 MB persist
  float* t1     = (float*)(ws + 116*MB);                    // 8 MB (phase A)
  float* pe_emb = (float*)(ws + 125*MB);                    // 8 MB (phase A)
  unsigned short* qb = (unsigned short*)(ws + 116*MB);      // 2 MB (phase B, t1 dead)
  float* candS = (float*)(ws + 121*MB);                     // 3.1 MB
  int*   candI = (int*)(ws + 127*MB);                       // 3.1 MB
  int*   topidx= (int*)(ws + 133*MB);                       // 128 KB

  dim3 blk(256);
  // --- encoders (fp32, query-precision-critical) ---
  k_gemm_f32<1,true ><<<dim3(16,16), blk, 0, stream>>>(patient, 320, nullptr, 0, pe_w1, pe_b1, t1, 1024, 320);
  k_gemm_f32<1,false><<<dim3(16,16), blk, 0, stream>>>(t1, 1024, nullptr, 0, pe_w2, pe_b2, pe_emb, 1024, 1024);
  k_gemm_f32<1,false><<<dim3(16,16), blk, 0, stream>>>(treatment, 64, nullptr, 0, te_w, te_b, te_emb, 1024, 64);
  k_gemm_f32<1,false><<<dim3(16,16), blk, 0, stream>>>(confounders, 256, nullptr, 0, ce_w, ce_b, ce_emb, 1024, 256);
  k_gemm_f32<2,true ><<<dim3(16,16), blk, 0, stream>>>(pe_emb, 1024, ce_emb, 1024, co_w1, co_b1, t2, 1024, 2048);
  k_gemm_f32<1,false><<<dim3(16, 8), blk, 0, stream>>>(t2, 1024, nullptr, 0, co_w2, co_b2, out_contr, 512, 1024);
  // --- fused normalize + bf16 convert ---
  k_norm_bf16<<<dim3(512),   blk, 0, stream>>>(out_contr, qb, 2048);
  k_norm_bf16<<<dim3(25000), blk, 0, stream>>>(corpus, cb, 100000);
  // --- similarity + top-k ---
  k_sim_topk<<<dim3(256), blk, 0, stream>>>(qb, cb, candS, candI);
  k_finalize<<<dim3(2048), blk, 0, stream>>>(candS, candI, out_contr, corpus, out_scores, out_idxf, topidx);
  // --- retrieval encoder + outcome head (bf16 MFMA) ---
  k_gather_bf16<<<dim3(2048), blk, 0, stream>>>(corpus, topidx, retr);
  k_transpose_bf16<<<dim3(256,32), blk, 0, stream>>>(re_w,  reT,  8192, 1024);
  k_transpose_bf16<<<dim3(96,32),  blk, 0, stream>>>(op_w1, op1T, 3072, 1024);
  k_transpose_bf16<<<dim3(32,16),  blk, 0, stream>>>(op_w2, op2T, 1024, 512);
  k_gemm_bf16<1,false,false,false><<<dim3(32,16), blk, 0, stream>>>(retr, 8192, nullptr, 0, nullptr, reT, re_b, re_out, 1024, 8192);
  k_gemm_bf16<3,true, true, true ><<<dim3(32,16), blk, 0, stream>>>(te_emb, 1024, ce_emb, 1024, re_out, op1T, op_b1, z1, 1024, 3072);
  k_gemm_bf16<1,false,true, false><<<dim3(32, 8), blk, 0, stream>>>(z1, 1024, nullptr, 0, nullptr, op2T, op_b2, z2, 512, 1024);
  k_gemv_out<<<dim3(512), blk, 0, stream>>>(z2, op_w3, op_b3, out_outcome);
}